// Round 3
// baseline (79.716 us; speedup 1.0000x reference)
//
#include <hip/hip_runtime.h>
#include <math.h>
#include <limits.h>

#define SIZE   256
#define NFACES 256
#define NVERTS 1024
#define NSPLIT 8     // 8 face-groups of 128 columns each (render block = 1024 threads)

// Two-kernel split: per-face prep runs ONCE (1 block) instead of 512x, and the
// render kernel loses the scattered gather chain, the ballot compaction, and
// two of its three barriers. R2 proved prep THROUGHPUT is irrelevant (halving
// it lost 3us) -- the target here is the render block's CRITICAL PATH.
//
// ws layout (floats):
//   [0] nv (int bits)   [1] zinit   [2..3] pad
//   [4 + slot*20 ...]   5 x float4 per kept face:
//     r0: xmin xmax ymin ymax      (bbox cull)
//     r1: ax ay bx by
//     r2: cx cy z0i z1i
//     r3: z2i A  u0x' u0y'         (u' = (2u-1)*zinv, pre-multiplied)
//     r4: u1x' u1y' u2x' u2y'
// Only faces with A >= 1e-9 are kept (view-independent; cullmask & A>=1e-9
// == A>=1e-9 since face-normal z is the same fp expression as A, and
// A>=1e-9 => Asafe == A; validated prior session). Slot order ascends in
// face id, so argmax-first-max == strict > scan + slot tie-break.

__global__ __launch_bounds__(256) void prep_kernel(
    const float* __restrict__ vertices,  // (1024,3)
    const int*   __restrict__ faces,     // (256,3)
    const float* __restrict__ uv,        // (1024,2)
    const int*   __restrict__ uvfaces,   // (256,3)
    float* __restrict__ ws)
{
#pragma clang fp contract(off)
    __shared__ float wred[4];
    __shared__ int   wcnt[4];
    const int t    = threadIdx.x;        // 0..255 == face id
    const int lane = t & 63;
    const int wv   = t >> 6;

    // zinit = min over all 1024 vertex z
    {
        float m =    vertices[3*t         + 2];
        m = fminf(m, vertices[3*(t + 256) + 2]);
        m = fminf(m, vertices[3*(t + 512) + 2]);
        m = fminf(m, vertices[3*(t + 768) + 2]);
        for (int off = 32; off > 0; off >>= 1) m = fminf(m, __shfl_down(m, off));
        if (lane == 0) wred[wv] = m;
    }

    const int i0 = faces[3*t+0], i1 = faces[3*t+1], i2 = faces[3*t+2];
    const float ax = vertices[3*i0+0], ay = vertices[3*i0+1], az = vertices[3*i0+2];
    const float bx = vertices[3*i1+0], by = vertices[3*i1+1], bz = vertices[3*i1+2];
    const float cx = vertices[3*i2+0], cy = vertices[3*i2+1], cz = vertices[3*i2+2];
    const float A  = (bx-ax)*(cy-ay) - (by-ay)*(cx-ax);
    const bool keep = (A >= 1e-9f);
    const unsigned long long bmask = __ballot(keep);
    const int rank = __popcll(bmask & ((1ull << lane) - 1ull));
    if (lane == 0) wcnt[wv] = (int)__popcll(bmask);
    __syncthreads();

    if (t == 0) {
        ((int*)ws)[0] = wcnt[0] + wcnt[1] + wcnt[2] + wcnt[3];
        ws[1] = fminf(fminf(wred[0], wred[1]), fminf(wred[2], wred[3]));
    }
    if (keep) {
        int base = 0;
        #pragma unroll
        for (int w = 0; w < 4; ++w) if (w < wv) base += wcnt[w];
        const int slot = base + rank;
        const float z0i = 1.0f/az, z1i = 1.0f/bz, z2i = 1.0f/cz;
        const int j0 = uvfaces[3*t+0], j1 = uvfaces[3*t+1], j2 = uvfaces[3*t+2];
        const float2 u0 = *reinterpret_cast<const float2*>(&uv[2*j0]);
        const float2 u1 = *reinterpret_cast<const float2*>(&uv[2*j1]);
        const float2 u2 = *reinterpret_cast<const float2*>(&uv[2*j2]);
        float4* rec = reinterpret_cast<float4*>(ws + 4) + slot*5;
        rec[0] = make_float4(fminf(fminf(ax,bx),cx), fmaxf(fmaxf(ax,bx),cx),
                             fminf(fminf(ay,by),cy), fmaxf(fmaxf(ay,by),cy));
        rec[1] = make_float4(ax, ay, bx, by);
        rec[2] = make_float4(cx, cy, z0i, z1i);
        rec[3] = make_float4(z2i, A,
                             (u0.x*2.0f - 1.0f) * z0i,
                             (u0.y*2.0f - 1.0f) * z0i);
        rec[4] = make_float4((u1.x*2.0f - 1.0f) * z1i,
                             (u1.y*2.0f - 1.0f) * z1i,
                             (u2.x*2.0f - 1.0f) * z2i,
                             (u2.y*2.0f - 1.0f) * z2i);
    }
}

// grid (2, 256): blockIdx.y = row, blockIdx.x = column half (R0 geometry:
// 512 blocks x 16 waves = 2 blocks/CU = 32 waves/CU, the occupancy cap --
// proven best in R0/R1/R2). Group g = t>>7 walks its chunk of the compact
// list straight from global (20 KB, L2-resident, loop-affine broadcast
// addresses -> deep pipelining, no LDS staging, no prep phase, ONE barrier).
// bbox cull is wave-uniform: py is block-uniform, x-span wave-uniform.
__global__ __launch_bounds__(1024) void render_kernel(
    const float* __restrict__ uvmap,     // (3,256,256)
    const float* __restrict__ ws,
    float* __restrict__ out)             // (4,256,256)
{
#pragma clang fp contract(off)
    __shared__ float sh_best[NSPLIT][128];
    __shared__ int   sh_slot[NSPLIT][128];

    const int t    = threadIdx.x;
    const int half = blockIdx.x;             // 0..1
    const int row  = blockIdx.y;             // 0..255
    const int col  = (t & 127) + 128 * half;
    const int grp  = t >> 7;                 // 0..7

    // pts[i,j] = (lin[j], lin[255-i]); linspace f64 -> f32 (numpy style)
    const float px = (float)(-1.0 + (double)col         * (2.0/255.0));
    const float py = (float)(-1.0 + (double)(255 - row) * (2.0/255.0));

    const int   nv    = ((const int*)ws)[0];
    const float zinit = ws[1];
    const float4* __restrict__ recs = reinterpret_cast<const float4*>(ws + 4);

    // wave-uniform x-span (each wave = 64 contiguous columns)
    const int   c0   = ((t >> 6) & 1) * 64 + 128 * half;
    const float pxlo = (float)(-1.0 + (double)c0        * (2.0/255.0));
    const float pxhi = (float)(-1.0 + (double)(c0 + 63) * (2.0/255.0));

    const int cs = (nv + NSPLIT - 1) / NSPLIT;
    int f0 = grp * cs; if (f0 > nv) f0 = nv;
    int f1 = f0 + cs;  if (f1 > nv) f1 = nv;

    float best  = -INFINITY;
    int   wslot = 0;
    for (int i = f0; i < f1; ++i) {
        const float4 bb = recs[i*5];         // xmin xmax ymin ymax
        // wave-uniform bbox cull (1e-4 margin, validated prior session):
        // x-span uniform per wave, py uniform per block -> scalar branch.
        if (bb.y + 1e-4f < pxlo || bb.x - 1e-4f > pxhi ||
            py <= bb.z - 1e-4f || py >= bb.w + 1e-4f) continue;
        const float4 r1 = recs[i*5+1];       // ax ay bx by
        const float4 r2 = recs[i*5+2];       // cx cy z0i z1i
        const float4 r3 = recs[i*5+3];       // z2i A u0x u0y
        const float pAB = (px - r1.z)*(r1.y - r1.w) - (py - r1.w)*(r1.x - r1.z);
        const float pCB = (px - r2.x)*(r1.w - r2.y) - (py - r2.y)*(r1.z - r2.x);
        const float pCA = (px - r1.x)*(r2.y - r1.y) - (py - r1.y)*(r2.x - r1.x);
        if (pAB > 0.0f && pCB > 0.0f && pCA > 0.0f) {
            const float w1 = pCB / r3.y;
            const float w2 = pCA / r3.y;
            const float w3 = (1.0f - w1) - w2;
            const float zp = (w1*r2.z + w2*r2.w) + w3*r3.x;
            const float z  = 1.0f / zp;                // ptsZ
            // ascending slot scan: strict > == numpy argmax first-max
            if (z >= zinit && z > best) { best = z; wslot = i; }
        }
    }
    sh_best[grp][t & 127] = best;
    sh_slot[grp][t & 127] = wslot;
    __syncthreads();                         // the ONLY barrier

    // ---- combine 8 groups + epilogue: threads 0..127 (one per column) ----
    if (t < 128) {
        best = -INFINITY; wslot = 0;
        #pragma unroll
        for (int g = 0; g < NSPLIT; ++g) {   // groups ascend in slot; strict >
            const float z = sh_best[g][t];   // + slot tie-break == first-max
            const int   s = sh_slot[g][t];
            if (z > best || (z == best && s < wslot)) { best = z; wslot = s; }
        }

        const bool  hit = (best > -INFINITY);
        const float hf  = hit ? 1.0f : 0.0f;
        float r0v = 0.0f, r1v = 0.0f, r2v = 0.0f;

        if (hit) {
            const float4 r1 = recs[wslot*5+1];
            const float4 r2 = recs[wslot*5+2];
            const float4 r3 = recs[wslot*5+3];
            const float4 r4 = recs[wslot*5+4];
            const float pCB = (px - r2.x)*(r1.w - r2.y) - (py - r2.y)*(r1.z - r2.x);
            const float pCA = (px - r1.x)*(r2.y - r1.y) - (py - r1.y)*(r2.x - r1.x);
            const float w1 = pCB / r3.y;
            const float w2 = pCA / r3.y;
            const float w3 = (1.0f - w1) - w2;
            const float p3 = (w1*r3.z + w2*r4.x) + w3*r4.z;  // uv.x * zinv interp
            const float p4 = (w1*r3.w + w2*r4.y) + w3*r4.w;  // uv.y * zinv interp
            const float p8 = (w1*r2.z + w2*r2.w) + w3*r3.x;  // zinv interp
            const float Zw = 1.0f / p8;
            const float gx = p3 * Zw;
            const float gy = p4 * Zw;

            // bilinear_sample(uvmap, gx, gy), zero padding, W=H=256
            const float x = ((gx + 1.0f)*256.0f - 1.0f)*0.5f;
            const float y = ((gy + 1.0f)*256.0f - 1.0f)*0.5f;
            const float x0f = floorf(x), y0f = floorf(y);
            const float x1f = x0f + 1.0f, y1f = y0f + 1.0f;
            const float wx1 = x - x0f, wx0 = 1.0f - wx1;
            const float wy1 = y - y0f, wy0 = 1.0f - wy1;
            const float w00 = wx0*wy0, w10 = wx1*wy0, w01 = wx0*wy1, w11 = wx1*wy1;

            // corner order matches reference add order
            {
                const bool v = (x0f >= 0.0f) && (x0f <= 255.0f) && (y0f >= 0.0f) && (y0f <= 255.0f);
                const int ix = (int)fminf(fmaxf(x0f, 0.0f), 255.0f);
                const int iy = (int)fminf(fmaxf(y0f, 0.0f), 255.0f);
                const int o  = iy*256 + ix;
                const float g0 = v ? uvmap[o]          : 0.0f;
                const float g1 = v ? uvmap[65536 + o]  : 0.0f;
                const float g2 = v ? uvmap[131072 + o] : 0.0f;
                r0v = r0v + g0*w00; r1v = r1v + g1*w00; r2v = r2v + g2*w00;
            }
            {
                const bool v = (x1f >= 0.0f) && (x1f <= 255.0f) && (y0f >= 0.0f) && (y0f <= 255.0f);
                const int ix = (int)fminf(fmaxf(x1f, 0.0f), 255.0f);
                const int iy = (int)fminf(fmaxf(y0f, 0.0f), 255.0f);
                const int o  = iy*256 + ix;
                const float g0 = v ? uvmap[o]          : 0.0f;
                const float g1 = v ? uvmap[65536 + o]  : 0.0f;
                const float g2 = v ? uvmap[131072 + o] : 0.0f;
                r0v = r0v + g0*w10; r1v = r1v + g1*w10; r2v = r2v + g2*w10;
            }
            {
                const bool v = (x0f >= 0.0f) && (x0f <= 255.0f) && (y1f >= 0.0f) && (y1f <= 255.0f);
                const int ix = (int)fminf(fmaxf(x0f, 0.0f), 255.0f);
                const int iy = (int)fminf(fmaxf(y1f, 0.0f), 255.0f);
                const int o  = iy*256 + ix;
                const float g0 = v ? uvmap[o]          : 0.0f;
                const float g1 = v ? uvmap[65536 + o]  : 0.0f;
                const float g2 = v ? uvmap[131072 + o] : 0.0f;
                r0v = r0v + g0*w01; r1v = r1v + g1*w01; r2v = r2v + g2*w01;
            }
            {
                const bool v = (x1f >= 0.0f) && (x1f <= 255.0f) && (y1f >= 0.0f) && (y1f <= 255.0f);
                const int ix = (int)fminf(fmaxf(x1f, 0.0f), 255.0f);
                const int iy = (int)fminf(fmaxf(y1f, 0.0f), 255.0f);
                const int o  = iy*256 + ix;
                const float g0 = v ? uvmap[o]          : 0.0f;
                const float g1 = v ? uvmap[65536 + o]  : 0.0f;
                const float g2 = v ? uvmap[131072 + o] : 0.0f;
                r0v = r0v + g0*w11; r1v = r1v + g1*w11; r2v = r2v + g2*w11;
            }
        }

        const int pix = row*256 + col;
        out[           pix] = r0v*hf;
        out[ 65536 +   pix] = r1v*hf;
        out[131072 +   pix] = r2v*hf;
        out[196608 +   pix] = hf;
    }
}

extern "C" void kernel_launch(void* const* d_in, const int* in_sizes, int n_in,
                              void* d_out, int out_size, void* d_ws, size_t ws_size,
                              hipStream_t stream) {
    const float* vertices = (const float*)d_in[0];
    const int*   faces    = (const int*)  d_in[1];
    const float* uv       = (const float*)d_in[2];
    const int*   uvfaces  = (const int*)  d_in[3];
    const float* uvmap    = (const float*)d_in[4];
    float*       out      = (float*)d_out;
    float*       ws       = (float*)d_ws;

    prep_kernel<<<1, 256, 0, stream>>>(vertices, faces, uv, uvfaces, ws);
    dim3 grid(2, SIZE);
    render_kernel<<<grid, 1024, 0, stream>>>(uvmap, ws, out);
}

// Round 4
// 75.258 us; speedup vs baseline: 1.0592x; 1.0592x over previous
//
#include <hip/hip_runtime.h>
#include <math.h>
#include <limits.h>

#define SIZE   256
#define NFACES 256
#define NVERTS 1024
#define NSPLIT 8     // 8 face-groups of 128 columns each (block = 1024 threads)

// R0 geometry (proven best in R0-R3): grid (2,256), 1024 threads, 16 waves,
// single kernel. R4 change: prep's dependent scattered gather chain
// (faces->vertices, uvfaces->uv; 2-3 serial cold-miss round trips after the
// harness's 256MiB fill evicts L2/L3) is replaced by ONE parallel coalesced
// staging pass into LDS; prep then gathers from LDS (~120cy/level). The
// ballot compaction is dropped: slot == face id, culled faces get an INF
// bbox sentinel, y-cull moves into the loop's wave-uniform bbox test
// (py block-uniform, x-span wave-uniform -> scalar branch; 1e-4 margin
// validated in prior sessions: fp edge noise <= ~5e-7*scale cannot flip the
// reference sign test).
//
// LDS face record fdl[face*5 + k]:
//   r0: xmin xmax ymin ymax   (INF,-INF,INF,-INF sentinel if A < 1e-9)
//   r1: ax ay bx by
//   r2: cx cy z0i z1i
//   r3: z2i A  u0x' u0y'      (u' = (2u-1)*zinv pre-multiplied)
//   r4: u1x' u1y' u2x' u2y'
// A >= 1e-9 == cullmask & (A>=1e-9) (face-normal z is the same fp expression
// as A) and implies Asafe == A. Ascending face id scan + strict > ==
// numpy argmax first-max.
__global__ __launch_bounds__(1024) void render_kernel(
    const float* __restrict__ vertices,  // (1024,3)
    const int*   __restrict__ faces,     // (256,3)
    const float* __restrict__ uv,        // (1024,2)
    const int*   __restrict__ uvfaces,   // (256,3)
    const float* __restrict__ uvmap,     // (3,256,256)
    float* __restrict__ out)             // (4,256,256)
{
#pragma clang fp contract(off)
    __shared__ float  sv[NVERTS*3];      // 12 KB staged vertices
    __shared__ int    sf[NFACES*3];      //  3 KB staged faces
    __shared__ int    suvf[NFACES*3];    //  3 KB staged uvfaces
    __shared__ float  suv[NVERTS*2];     //  8 KB staged uv
    __shared__ float4 fdl[NFACES*5];     // 20 KB face records
    __shared__ float  sh_best[NSPLIT][128];
    __shared__ int    sh_slot[NSPLIT][128];
    __shared__ float  wred[16];

    const int t    = threadIdx.x;
    const int lane = t & 63;
    const int wv   = t >> 6;                 // wave 0..15
    const int half = blockIdx.x;             // 0..1
    const int row  = blockIdx.y;             // 0..255
    const int col  = (t & 127) + 128 * half;
    const int grp  = t >> 7;                 // 0..7

    // pts[i,j] = (lin[j], lin[255-i]); linspace f64 -> f32 (numpy style)
    const float px = (float)(-1.0 + (double)col         * (2.0/255.0));
    const float py = (float)(-1.0 + (double)(255 - row) * (2.0/255.0));

    // ---- zinit partial from GLOBAL (overlaps staging; consumed after bar 2) ----
    {
        float m = vertices[3*t + 2];
        for (int off = 32; off > 0; off >>= 1) m = fminf(m, __shfl_down(m, off));
        if (lane == 0) wred[wv] = m;
    }

    // ---- coalesced staging: one parallel round trip, no dependent chain ----
    sv[t]        = vertices[t];
    sv[t + 1024] = vertices[t + 1024];
    sv[t + 2048] = vertices[t + 2048];
    suv[t]        = uv[t];
    suv[t + 1024] = uv[t + 1024];
    if (t < NFACES*3) {                      // 12 waves, wave-uniform branch
        sf[t]   = faces[t];
        suvf[t] = uvfaces[t];
    }
    __syncthreads();   // staging published

    // ---- per-face prep from LDS: thread t < 256 handles face t (slot==t) ----
    if (t < NFACES) {
        const int i0 = sf[3*t+0], i1 = sf[3*t+1], i2 = sf[3*t+2];
        const float ax = sv[3*i0+0], ay = sv[3*i0+1], az = sv[3*i0+2];
        const float bx = sv[3*i1+0], by = sv[3*i1+1], bz = sv[3*i1+2];
        const float cx = sv[3*i2+0], cy = sv[3*i2+1], cz = sv[3*i2+2];
        const float A  = (bx-ax)*(cy-ay) - (by-ay)*(cx-ax);
        float4* rec = &fdl[t*5];
        if (A >= 1e-9f) {
            const float z0i = 1.0f/az, z1i = 1.0f/bz, z2i = 1.0f/cz;
            const int j0 = suvf[3*t+0], j1 = suvf[3*t+1], j2 = suvf[3*t+2];
            rec[0] = make_float4(fminf(fminf(ax,bx),cx), fmaxf(fmaxf(ax,bx),cx),
                                 fminf(fminf(ay,by),cy), fmaxf(fmaxf(ay,by),cy));
            rec[1] = make_float4(ax, ay, bx, by);
            rec[2] = make_float4(cx, cy, z0i, z1i);
            rec[3] = make_float4(z2i, A,
                                 (suv[2*j0+0]*2.0f - 1.0f) * z0i,
                                 (suv[2*j0+1]*2.0f - 1.0f) * z0i);
            rec[4] = make_float4((suv[2*j1+0]*2.0f - 1.0f) * z1i,
                                 (suv[2*j1+1]*2.0f - 1.0f) * z1i,
                                 (suv[2*j2+0]*2.0f - 1.0f) * z2i,
                                 (suv[2*j2+1]*2.0f - 1.0f) * z2i);
        } else {
            rec[0] = make_float4(INFINITY, -INFINITY, INFINITY, -INFINITY);
        }
    }
    __syncthreads();   // fdl published (wred was published before barrier 1)

    float zinit;
    {
        float mm = wred[0];
        #pragma unroll
        for (int i = 1; i < 16; ++i) mm = fminf(mm, wred[i]);
        zinit = mm;
    }

    // wave-uniform x-span (each wave = 64 contiguous columns)
    const int   c0   = ((t >> 6) & 1) * 64 + 128 * half;
    const float pxlo = (float)(-1.0 + (double)c0        * (2.0/255.0));
    const float pxhi = (float)(-1.0 + (double)(c0 + 63) * (2.0/255.0));

    float best  = -INFINITY;
    int   wslot = 0;
    const int f0 = grp * (NFACES / NSPLIT);        // fixed 32-face chunk
    for (int i = f0; i < f0 + NFACES/NSPLIT; ++i) {
        const float4 bb = fdl[i*5];          // xmin xmax ymin ymax (broadcast)
        // wave-uniform bbox cull, incl. y (sentinel rejects A-culled faces)
        if (bb.y + 1e-4f < pxlo || bb.x - 1e-4f > pxhi ||
            py <= bb.z - 1e-4f || py >= bb.w + 1e-4f) continue;
        const float4 r1 = fdl[i*5+1];        // ax ay bx by
        const float4 r2 = fdl[i*5+2];        // cx cy z0i z1i
        const float4 r3 = fdl[i*5+3];        // z2i A u0x u0y
        const float pAB = (px - r1.z)*(r1.y - r1.w) - (py - r1.w)*(r1.x - r1.z);
        const float pCB = (px - r2.x)*(r1.w - r2.y) - (py - r2.y)*(r1.z - r2.x);
        const float pCA = (px - r1.x)*(r2.y - r1.y) - (py - r1.y)*(r2.x - r1.x);
        if (pAB > 0.0f && pCB > 0.0f && pCA > 0.0f) {
            const float w1 = pCB / r3.y;
            const float w2 = pCA / r3.y;
            const float w3 = (1.0f - w1) - w2;
            const float zp = (w1*r2.z + w2*r2.w) + w3*r3.x;
            const float z  = 1.0f / zp;                // ptsZ
            // ascending face-id scan: strict > == numpy argmax first-max
            if (z >= zinit && z > best) { best = z; wslot = i; }
        }
    }
    sh_best[grp][t & 127] = best;
    sh_slot[grp][t & 127] = wslot;
    __syncthreads();

    // ---- combine 8 groups + epilogue: threads 0..127 (one per column) ----
    if (t < 128) {
        best = -INFINITY; wslot = 0;
        #pragma unroll
        for (int g = 0; g < NSPLIT; ++g) {   // groups ascend in face id; strict >
            const float z = sh_best[g][t];   // + slot tie-break == first-max
            const int   s = sh_slot[g][t];
            if (z > best || (z == best && s < wslot)) { best = z; wslot = s; }
        }

        const bool  hit = (best > -INFINITY);
        const float hf  = hit ? 1.0f : 0.0f;
        float r0v = 0.0f, r1v = 0.0f, r2v = 0.0f;

        if (hit) {
            const float4 r1 = fdl[wslot*5+1];
            const float4 r2 = fdl[wslot*5+2];
            const float4 r3 = fdl[wslot*5+3];
            const float4 r4 = fdl[wslot*5+4];
            const float pCB = (px - r2.x)*(r1.w - r2.y) - (py - r2.y)*(r1.z - r2.x);
            const float pCA = (px - r1.x)*(r2.y - r1.y) - (py - r1.y)*(r2.x - r1.x);
            const float w1 = pCB / r3.y;
            const float w2 = pCA / r3.y;
            const float w3 = (1.0f - w1) - w2;
            const float p3 = (w1*r3.z + w2*r4.x) + w3*r4.z;  // uv.x * zinv interp
            const float p4 = (w1*r3.w + w2*r4.y) + w3*r4.w;  // uv.y * zinv interp
            const float p8 = (w1*r2.z + w2*r2.w) + w3*r3.x;  // zinv interp
            const float Zw = 1.0f / p8;
            const float gx = p3 * Zw;
            const float gy = p4 * Zw;

            // bilinear_sample(uvmap, gx, gy), zero padding, W=H=256
            const float x = ((gx + 1.0f)*256.0f - 1.0f)*0.5f;
            const float y = ((gy + 1.0f)*256.0f - 1.0f)*0.5f;
            const float x0f = floorf(x), y0f = floorf(y);
            const float x1f = x0f + 1.0f, y1f = y0f + 1.0f;
            const float wx1 = x - x0f, wx0 = 1.0f - wx1;
            const float wy1 = y - y0f, wy0 = 1.0f - wy1;
            const float w00 = wx0*wy0, w10 = wx1*wy0, w01 = wx0*wy1, w11 = wx1*wy1;

            // corner order matches reference add order
            {
                const bool v = (x0f >= 0.0f) && (x0f <= 255.0f) && (y0f >= 0.0f) && (y0f <= 255.0f);
                const int ix = (int)fminf(fmaxf(x0f, 0.0f), 255.0f);
                const int iy = (int)fminf(fmaxf(y0f, 0.0f), 255.0f);
                const int o  = iy*256 + ix;
                const float g0 = v ? uvmap[o]          : 0.0f;
                const float g1 = v ? uvmap[65536 + o]  : 0.0f;
                const float g2 = v ? uvmap[131072 + o] : 0.0f;
                r0v = r0v + g0*w00; r1v = r1v + g1*w00; r2v = r2v + g2*w00;
            }
            {
                const bool v = (x1f >= 0.0f) && (x1f <= 255.0f) && (y0f >= 0.0f) && (y0f <= 255.0f);
                const int ix = (int)fminf(fmaxf(x1f, 0.0f), 255.0f);
                const int iy = (int)fminf(fmaxf(y0f, 0.0f), 255.0f);
                const int o  = iy*256 + ix;
                const float g0 = v ? uvmap[o]          : 0.0f;
                const float g1 = v ? uvmap[65536 + o]  : 0.0f;
                const float g2 = v ? uvmap[131072 + o] : 0.0f;
                r0v = r0v + g0*w10; r1v = r1v + g1*w10; r2v = r2v + g2*w10;
            }
            {
                const bool v = (x0f >= 0.0f) && (x0f <= 255.0f) && (y1f >= 0.0f) && (y1f <= 255.0f);
                const int ix = (int)fminf(fmaxf(x0f, 0.0f), 255.0f);
                const int iy = (int)fminf(fmaxf(y1f, 0.0f), 255.0f);
                const int o  = iy*256 + ix;
                const float g0 = v ? uvmap[o]          : 0.0f;
                const float g1 = v ? uvmap[65536 + o]  : 0.0f;
                const float g2 = v ? uvmap[131072 + o] : 0.0f;
                r0v = r0v + g0*w01; r1v = r1v + g1*w01; r2v = r2v + g2*w01;
            }
            {
                const bool v = (x1f >= 0.0f) && (x1f <= 255.0f) && (y1f >= 0.0f) && (y1f <= 255.0f);
                const int ix = (int)fminf(fmaxf(x1f, 0.0f), 255.0f);
                const int iy = (int)fminf(fmaxf(y1f, 0.0f), 255.0f);
                const int o  = iy*256 + ix;
                const float g0 = v ? uvmap[o]          : 0.0f;
                const float g1 = v ? uvmap[65536 + o]  : 0.0f;
                const float g2 = v ? uvmap[131072 + o] : 0.0f;
                r0v = r0v + g0*w11; r1v = r1v + g1*w11; r2v = r2v + g2*w11;
            }
        }

        const int pix = row*256 + col;
        out[           pix] = r0v*hf;
        out[ 65536 +   pix] = r1v*hf;
        out[131072 +   pix] = r2v*hf;
        out[196608 +   pix] = hf;
    }
}

extern "C" void kernel_launch(void* const* d_in, const int* in_sizes, int n_in,
                              void* d_out, int out_size, void* d_ws, size_t ws_size,
                              hipStream_t stream) {
    const float* vertices = (const float*)d_in[0];
    const int*   faces    = (const int*)  d_in[1];
    const float* uv       = (const float*)d_in[2];
    const int*   uvfaces  = (const int*)  d_in[3];
    const float* uvmap    = (const float*)d_in[4];
    float*       out      = (float*)d_out;

    dim3 grid(2, SIZE);
    render_kernel<<<grid, 1024, 0, stream>>>(vertices, faces, uv, uvfaces, uvmap, out);
}